// Round 2
// baseline (1972.990 us; speedup 1.0000x reference)
//
#include <hip/hip_runtime.h>

#define NB 131072
#define ND 512
#define NK 64
#define NCB 1024

// ---------------------------------------------------------------------------
// Precompute: C_dec[c][d] = sum_k cb[c,k] * U[d,k]   (decoded codebook, 2 MB)
//             c_sq[c]     = ||cb[c]||^2
// ---------------------------------------------------------------------------
__global__ __launch_bounds__(256) void vq_precompute(
    const float* __restrict__ U, const float* __restrict__ cb,
    float* __restrict__ C_dec, float* __restrict__ c_sq)
{
    int t = blockIdx.x * 256 + threadIdx.x;   // 0 .. NCB*ND-1
    int c = t >> 9;                           // uniform within block
    int d = t & (ND - 1);
    const float* __restrict__ crow = cb + (size_t)c * NK;
    const float* __restrict__ urow = U + (size_t)d * NK;
    float a0 = 0.f, a1 = 0.f, a2 = 0.f, a3 = 0.f;
#pragma unroll
    for (int k = 0; k < NK; k += 4) {
        a0 = fmaf(crow[k + 0], urow[k + 0], a0);
        a1 = fmaf(crow[k + 1], urow[k + 1], a1);
        a2 = fmaf(crow[k + 2], urow[k + 2], a2);
        a3 = fmaf(crow[k + 3], urow[k + 3], a3);
    }
    C_dec[t] = (a0 + a1) + (a2 + a3);
    if (d == 0) {
        float s0 = 0.f, s1 = 0.f, s2 = 0.f, s3 = 0.f;
#pragma unroll
        for (int k = 0; k < NK; k += 4) {
            s0 = fmaf(crow[k + 0], crow[k + 0], s0);
            s1 = fmaf(crow[k + 1], crow[k + 1], s1);
            s2 = fmaf(crow[k + 2], crow[k + 2], s2);
            s3 = fmaf(crow[k + 3], crow[k + 3], s3);
        }
        c_sq[c] = (s0 + s1) + (s2 + s3);
    }
}

// ---------------------------------------------------------------------------
// Main kernel: block = 4 waves = 64 rows (row <-> lane).
//   Phase A: wave w computes z[:, 16w..16w+16) over full k.
//            U slice address is wave-uniform -> scalar loads; x via float4.
//   (exchange z slices through padded LDS tile: +1 pad -> 2-way bank alias, free)
//   Phase B: wave w scans codebook quarter [256w, 256w+256) (wave-uniform ->
//            scalar loads); cross-wave argmin reduce in ascending-w order with
//            strict < == global first-occurrence tie-break (np.argmin).
//   Phase C: idx (wave 0, coalesced), z_q slices (gather cb[fi], L2-resident).
//   x_recon handled by the separate coalesced vq_decode kernel.
// Grid = NB/64 = 2048 blocks x 4 waves = 8192 waves (4x round 1).
// ---------------------------------------------------------------------------
__global__ __launch_bounds__(256, 5) void vq_main2(
    const float* __restrict__ x, const float* __restrict__ U,
    const float* __restrict__ cb, const float* __restrict__ c_sq,
    float* __restrict__ out)
{
    __shared__ float zL[64][NK + 1];   // +1 pad: bank = (lane + k) % 32, 2-way
    __shared__ float redD[4][64];
    __shared__ int   redI[4][64];

    const int lane = threadIdx.x & 63;
    const int w    = threadIdx.x >> 6;
    const size_t row = (size_t)blockIdx.x * 64 + lane;

    // ---- Phase A: partial z (16 columns, full k) ----
    float zp[16];
#pragma unroll
    for (int j = 0; j < 16; ++j) zp[j] = 0.f;
    const float4* __restrict__ x4 = (const float4*)(x + row * ND);
    for (int k4 = 0; k4 < ND / 4; ++k4) {
        float4 xv = x4[k4];
        const float* __restrict__ u = U + (size_t)(4 * k4) * NK + w * 16;
#pragma unroll
        for (int j = 0; j < 16; ++j) zp[j] = fmaf(u[j], xv.x, zp[j]);
        u += NK;
#pragma unroll
        for (int j = 0; j < 16; ++j) zp[j] = fmaf(u[j], xv.y, zp[j]);
        u += NK;
#pragma unroll
        for (int j = 0; j < 16; ++j) zp[j] = fmaf(u[j], xv.z, zp[j]);
        u += NK;
#pragma unroll
        for (int j = 0; j < 16; ++j) zp[j] = fmaf(u[j], xv.w, zp[j]);
    }

    float* __restrict__ out_z   = out + (size_t)NB * ND;
    float* __restrict__ out_zq  = out_z + (size_t)NB * NK;
    float* __restrict__ out_idx = out_zq + (size_t)NB * NK;

    // write z slice (each lane writes one contiguous 64B cache line)
    {
        float4* __restrict__ oz = (float4*)(out_z + row * NK + w * 16);
#pragma unroll
        for (int q = 0; q < 4; ++q)
            oz[q] = make_float4(zp[4*q], zp[4*q+1], zp[4*q+2], zp[4*q+3]);
    }
    // stash z slice into LDS
#pragma unroll
    for (int j = 0; j < 16; ++j) zL[lane][w * 16 + j] = zp[j];
    __syncthreads();

    // gather full z for this lane's row
    float zf[NK];
#pragma unroll
    for (int k = 0; k < NK; ++k) zf[k] = zL[lane][k];

    // ---- Phase B: argmin over codebook quarter ----
    const int j0 = w * (NCB / 4);
    float best = 3.4e38f;
    int bidx = j0;
    for (int j = 0; j < NCB / 4; ++j) {
        const float* __restrict__ c = cb + (size_t)(j0 + j) * NK;
        float a0 = 0.f, a1 = 0.f, a2 = 0.f, a3 = 0.f;
#pragma unroll
        for (int k = 0; k < NK; k += 4) {
            a0 = fmaf(zf[k + 0], c[k + 0], a0);
            a1 = fmaf(zf[k + 1], c[k + 1], a1);
            a2 = fmaf(zf[k + 2], c[k + 2], a2);
            a3 = fmaf(zf[k + 3], c[k + 3], a3);
        }
        float dist = fmaf(-2.f, (a0 + a1) + (a2 + a3), c_sq[j0 + j]);
        if (dist < best) { best = dist; bidx = j0 + j; }   // strict < = first-min
    }
    redD[w][lane] = best;
    redI[w][lane] = bidx;
    __syncthreads();

    // cross-wave argmin, ascending w => global first-occurrence tie-break
    float fb = redD[0][lane];
    int   fi = redI[0][lane];
#pragma unroll
    for (int w2 = 1; w2 < 4; ++w2) {
        float d2 = redD[w2][lane];
        if (d2 < fb) { fb = d2; fi = redI[w2][lane]; }
    }

    if (w == 0) out_idx[(size_t)blockIdx.x * 64 + lane] = (float)fi;

    // z_q slice: gather cb[fi] (256 KB table, L2-resident)
    const float4* __restrict__ cq = (const float4*)(cb + (size_t)fi * NK + w * 16);
    float4* __restrict__ ozq = (float4*)(out_zq + row * NK + w * 16);
#pragma unroll
    for (int q = 0; q < 4; ++q) ozq[q] = cq[q];
}

// ---------------------------------------------------------------------------
// Decode: x_recon[r] = C_dec[idx[r]].  One wave covers half a row, so idx is
// wave-uniform -> fully coalesced 1KB reads and writes (no RMW amplification).
// ---------------------------------------------------------------------------
__global__ __launch_bounds__(256) void vq_decode(
    const float* __restrict__ out_idx, const float* __restrict__ C_dec,
    float* __restrict__ out_recon)
{
    const int t = blockIdx.x * 256 + threadIdx.x;
    const int r = t >> 7;          // row (uniform across each wave)
    const int q = t & 127;         // float4 index within row
    const int bi = (int)out_idx[r];
    ((float4*)out_recon)[(size_t)r * (ND / 4) + q] =
        ((const float4*)C_dec)[(size_t)bi * (ND / 4) + q];
}

// ---------------------------------------------------------------------------
// Fallback (ws too small): round-1 monolithic kernel, correctness only.
// ---------------------------------------------------------------------------
__global__ __launch_bounds__(256, 2) void vq_fallback(
    const float* __restrict__ x, const float* __restrict__ U,
    const float* __restrict__ cb, float* __restrict__ out)
{
    const int r = blockIdx.x * 256 + threadIdx.x;
    const float4* __restrict__ x4 = (const float4*)(x + (size_t)r * ND);

    float z[NK];
#pragma unroll
    for (int j = 0; j < NK; ++j) z[j] = 0.f;
    for (int k4 = 0; k4 < ND / 4; ++k4) {
        float4 xv = x4[k4];
        const float* __restrict__ u = U + (size_t)(4 * k4) * NK;
#pragma unroll
        for (int j = 0; j < NK; ++j) z[j] = fmaf(u[j], xv.x, z[j]);
        u += NK;
#pragma unroll
        for (int j = 0; j < NK; ++j) z[j] = fmaf(u[j], xv.y, z[j]);
        u += NK;
#pragma unroll
        for (int j = 0; j < NK; ++j) z[j] = fmaf(u[j], xv.z, z[j]);
        u += NK;
#pragma unroll
        for (int j = 0; j < NK; ++j) z[j] = fmaf(u[j], xv.w, z[j]);
    }

    float best = 3.4e38f;
    int bidx = 0;
    for (int j = 0; j < NCB; ++j) {
        const float* __restrict__ c = cb + (size_t)j * NK;
        float a0 = 0.f, a1 = 0.f, a2 = 0.f, a3 = 0.f;
        float s0 = 0.f, s1 = 0.f, s2 = 0.f, s3 = 0.f;
#pragma unroll
        for (int k = 0; k < NK; k += 4) {
            a0 = fmaf(z[k + 0], c[k + 0], a0);
            a1 = fmaf(z[k + 1], c[k + 1], a1);
            a2 = fmaf(z[k + 2], c[k + 2], a2);
            a3 = fmaf(z[k + 3], c[k + 3], a3);
            s0 = fmaf(c[k + 0], c[k + 0], s0);
            s1 = fmaf(c[k + 1], c[k + 1], s1);
            s2 = fmaf(c[k + 2], c[k + 2], s2);
            s3 = fmaf(c[k + 3], c[k + 3], s3);
        }
        float dist = fmaf(-2.f, (a0 + a1) + (a2 + a3), (s0 + s1) + (s2 + s3));
        if (dist < best) { best = dist; bidx = j; }
    }

    float* __restrict__ out_z   = out + (size_t)NB * ND;
    float* __restrict__ out_zq  = out_z + (size_t)NB * NK;
    float* __restrict__ out_idx = out_zq + (size_t)NB * NK;

    float4* __restrict__ oz = (float4*)(out_z + (size_t)r * NK);
#pragma unroll
    for (int q = 0; q < NK / 4; ++q)
        oz[q] = make_float4(z[4*q], z[4*q+1], z[4*q+2], z[4*q+3]);

    float zq[NK];
    const float4* __restrict__ crow4 = (const float4*)(cb + (size_t)bidx * NK);
    float4* __restrict__ ozq = (float4*)(out_zq + (size_t)r * NK);
#pragma unroll
    for (int q = 0; q < NK / 4; ++q) {
        float4 v = crow4[q];
        ozq[q] = v;
        zq[4*q] = v.x; zq[4*q+1] = v.y; zq[4*q+2] = v.z; zq[4*q+3] = v.w;
    }
    out_idx[r] = (float)bidx;

    float4* __restrict__ orc = (float4*)(out + (size_t)r * ND);
    for (int d = 0; d < ND; d += 4) {
        float r0 = 0.f, r1 = 0.f, r2 = 0.f, r3 = 0.f;
        const float* __restrict__ u0 = U + (size_t)(d + 0) * NK;
        const float* __restrict__ u1 = U + (size_t)(d + 1) * NK;
        const float* __restrict__ u2 = U + (size_t)(d + 2) * NK;
        const float* __restrict__ u3 = U + (size_t)(d + 3) * NK;
#pragma unroll
        for (int k = 0; k < NK; ++k) {
            r0 = fmaf(zq[k], u0[k], r0);
            r1 = fmaf(zq[k], u1[k], r1);
            r2 = fmaf(zq[k], u2[k], r2);
            r3 = fmaf(zq[k], u3[k], r3);
        }
        orc[d / 4] = make_float4(r0, r1, r2, r3);
    }
}

extern "C" void kernel_launch(void* const* d_in, const int* in_sizes, int n_in,
                              void* d_out, int out_size, void* d_ws, size_t ws_size,
                              hipStream_t stream) {
    const float* x  = (const float*)d_in[0];
    const float* U  = (const float*)d_in[1];
    const float* cb = (const float*)d_in[2];
    float* out = (float*)d_out;

    const size_t need = (size_t)NCB * ND * sizeof(float) + NCB * sizeof(float);
    if (ws_size >= need) {
        float* C_dec = (float*)d_ws;
        float* c_sq  = C_dec + (size_t)NCB * ND;
        vq_precompute<<<(NCB * ND) / 256, 256, 0, stream>>>(U, cb, C_dec, c_sq);
        vq_main2<<<NB / 64, 256, 0, stream>>>(x, U, cb, c_sq, out);
        const float* idxp = out + (size_t)NB * ND + 2 * (size_t)NB * NK;
        vq_decode<<<(NB * (ND / 4)) / 256, 256, 0, stream>>>(idxp, C_dec, out);
    } else {
        vq_fallback<<<NB / 256, 256, 0, stream>>>(x, U, cb, out);
    }
}